// Round 11
// baseline (360.820 us; speedup 1.0000x reference)
//
#include <hip/hip_runtime.h>
#include <math.h>

#define B_ 8
#define H_ 128
#define L_ 16384
#define N_ 16
#define CHUNK_ 64
#define NCH_ 256   // L_ / CHUNK_

typedef float f32x4 __attribute__((ext_vector_type(4)));
typedef short bf16x8 __attribute__((ext_vector_type(8)));

static __device__ __forceinline__ unsigned int f2bf(float f) {
  unsigned int u = __float_as_uint(f);
  return (u + 0x7FFFu + ((u >> 16) & 1u)) >> 16;   // RNE bf16
}
static __device__ __forceinline__ float bf2f(unsigned int us) {
  return __uint_as_float(us << 16);
}
// packed 2xbf16 from 2 f32 in one instruction
static __device__ __forceinline__ unsigned int cvtpk(float lo, float hi) {
  unsigned int r;
  asm("v_cvt_pk_bf16_f32 %0, %1, %2" : "=v"(r) : "v"(lo), "v"(hi));
  return r;
}

// ---------------------------------------------------------------------------
// prep2: parallel weight bf16 conversion + SSM constants + FiLM + BN zero
// ---------------------------------------------------------------------------
__global__ __launch_bounds__(256) void prep2_kernel(
    const float* __restrict__ lin_w, const float* __restrict__ out_w,
    const float* __restrict__ log_dt, const float* __restrict__ log_A_real,
    const float* __restrict__ A_imag, const float* __restrict__ C_re,
    const float* __restrict__ C_im, const float* __restrict__ cond,
    const float* __restrict__ film_w, const float* __restrict__ film_b,
    unsigned short* __restrict__ wA16, unsigned short* __restrict__ wB16,
    float* __restrict__ consts,
    float* __restrict__ gact, float* __restrict__ bact,
    float* __restrict__ bnsum, float* __restrict__ bnsumsq)
{
  int blk = blockIdx.x, t = threadIdx.x;
  if (blk < 16) {
    int base = blk * 1024;
    #pragma unroll
    for (int it = 0; it < 4; it++) {
      int i = base + it * 256 + t;
      wA16[i] = (unsigned short)f2bf(lin_w[i]);
      wB16[i] = (unsigned short)f2bf(out_w[i]);
    }
  } else if (blk == 16) {
    for (int i = t; i < H_ * N_; i += 256) {
      int h = i >> 4, n = i & 15;
      float dt  = expf(log_dt[h]);
      float Are = -expf(log_A_real[i]);
      float Aim = A_imag[i];
      float dre = dt * Are, dim = dt * Aim;
      float er  = expf(dre);
      float wre = er * cosf(dim);
      float wim = er * sinf(dim);
      float den = Are * Are + Aim * Aim;
      float nre = wre - 1.0f, nim = wim;
      float dBre = (nre * Are + nim * Aim) / den;
      float dBim = (nim * Are - nre * Aim) / den;
      float cr = C_re[i], ci = C_im[i];
      float cere = cr * dBre - ci * dBim;
      float ceim = cr * dBim + ci * dBre;
      float e2   = expf((float)CHUNK_ * dre);
      float wcre = e2 * cosf((float)CHUNK_ * dim);
      float wcim = e2 * sinf((float)CHUNK_ * dim);
      float* cb = consts + h * 96;
      cb[n]      = wre;  cb[16 + n] = wim;
      cb[32 + n] = cere; cb[48 + n] = ceim;
      cb[64 + n] = wcre; cb[80 + n] = wcim;
    }
    if (t < 128) bnsum[t] = 0.0f;
    else         bnsumsq[t - 128] = 0.0f;
  } else {
    for (int i = t; i < B_ * 2 * H_; i += 256) {
      int b = i >> 8, k = i & 255;
      float acc = film_b[k];
      #pragma unroll
      for (int c = 0; c < 4; c++) acc += cond[b * 4 + c] * film_w[k * 4 + c];
      if (k < H_) gact[b * H_ + k] = acc;
      else        bact[b * H_ + (k - H_)] = acc;
    }
  }
}

// ---------------------------------------------------------------------------
// MFMA GEMM, 128g x 128j tile, K=128.  MODE 0: x f32 -> u bf16 (+prelu).
// MODE 1: y bf16 -> z bf16 (+bias) + fused BN partial sums (LDS + 1 global
// f32 atomic per g per block — round-3-proven).  bf16 intermediates in the
// first 32KB of each row's 64KB f32 slot in d_out.  Col-disjoint -> in-place
// safe.  Staging packs via v_cvt_pk_bf16_f32 (MODE0) / v_perm_b32 (MODE1).
// ---------------------------------------------------------------------------
template<int MODE>
__global__ __launch_bounds__(256) void mgemm_kernel(
    const void* inv, const unsigned short* __restrict__ w16,
    const float* __restrict__ bias, const float* __restrict__ prelu_a,
    unsigned short* __restrict__ outb,
    float* __restrict__ bnsum, float* __restrict__ bnsumsq)
{
  __shared__ __align__(16) unsigned short xT[128 * 128];  // 32KB swizzled [j][h]
  __shared__ float bs1[128], bs2[128];
  char* xb = (char*)xT;
  int tid = threadIdx.x;
  int blk = blockIdx.x;
  int b   = blk >> 7;
  int jb  = (blk & 127) << 7;

  if (MODE == 1 && tid < 128) { bs1[tid] = 0.0f; bs2[tid] = 0.0f; }

  // ---- stage x^T tile (128j x 128h) as bf16, XOR-swizzled ----
  {
    int hp = tid >> 4;        // h-group: h0 = hp*8
    int jq = tid & 15;        // j-group: j0 = jq*8
    int h0 = hp << 3;
    int j0 = jq << 3;
    if (MODE == 0) {
      const float* inb = (const float*)inv + ((size_t)b * H_) * L_ + jb;
      f32x4 r[8][2];
      #pragma unroll
      for (int rr = 0; rr < 8; rr++) {
        r[rr][0] = *reinterpret_cast<const f32x4*>(&inb[(size_t)(h0 + rr) * L_ + j0]);
        r[rr][1] = *reinterpret_cast<const f32x4*>(&inb[(size_t)(h0 + rr) * L_ + j0 + 4]);
      }
      #pragma unroll
      for (int jj = 0; jj < 8; jj++) {
        int j = j0 + jj;
        uint4 pk;
        #define GE_(rr) ((jj < 4) ? r[rr][0][jj] : r[rr][1][jj - 4])
        pk.x = cvtpk(GE_(0), GE_(1));
        pk.y = cvtpk(GE_(2), GE_(3));
        pk.z = cvtpk(GE_(4), GE_(5));
        pk.w = cvtpk(GE_(6), GE_(7));
        #undef GE_
        int addr = j * 256 + ((hp << 4) ^ ((j & 15) << 4));
        *reinterpret_cast<uint4*>(xb + addr) = pk;
      }
    } else {
      const unsigned short* ub = (const unsigned short*)inv;
      uint4 rv[8];
      #pragma unroll
      for (int rr = 0; rr < 8; rr++)
        rv[rr] = *reinterpret_cast<const uint4*>(
            ub + ((size_t)(b * H_ + h0 + rr)) * 32768 + jb + j0);
      #pragma unroll
      for (int jj = 0; jj < 8; jj++) {
        int j = j0 + jj;
        unsigned int sel = (jj & 1) ? 0x07060302u : 0x05040100u;
        uint4 pk;
        #define WD_(rr) ((jj >> 1) == 0 ? rv[rr].x : (jj >> 1) == 1 ? rv[rr].y : \
                         (jj >> 1) == 2 ? rv[rr].z : rv[rr].w)
        pk.x = __builtin_amdgcn_perm(WD_(1), WD_(0), sel);
        pk.y = __builtin_amdgcn_perm(WD_(3), WD_(2), sel);
        pk.z = __builtin_amdgcn_perm(WD_(5), WD_(4), sel);
        pk.w = __builtin_amdgcn_perm(WD_(7), WD_(6), sel);
        #undef WD_
        int addr = j * 256 + ((hp << 4) ^ ((j & 15) << 4));
        *reinterpret_cast<uint4*>(xb + addr) = pk;
      }
    }
  }
  __syncthreads();

  // ---- MFMA compute: wave tile 64g x 64j ----
  int lane = tid & 63;
  int w    = tid >> 6;
  int wg   = w >> 1;
  int wj   = w & 1;
  int ln   = lane & 15;
  int q    = lane >> 4;
  f32x4 acc[4][4];
  #pragma unroll
  for (int mi = 0; mi < 4; mi++)
    #pragma unroll
    for (int n = 0; n < 4; n++) acc[mi][n] = (f32x4)0.0f;

  #pragma unroll
  for (int kb = 0; kb < 4; kb++) {
    bf16x8 a[4], bv[4];
    #pragma unroll
    for (int mi = 0; mi < 4; mi++)
      a[mi] = *reinterpret_cast<const bf16x8*>(
          &w16[(size_t)(wg * 64 + mi * 16 + ln) * 128 + kb * 32 + q * 8]);
    #pragma unroll
    for (int n = 0; n < 4; n++) {
      int jl = wj * 64 + n * 16 + ln;
      int ar = jl * 256 + (((kb << 6) + (q << 4)) ^ ((jl & 15) << 4));
      bv[n] = *reinterpret_cast<bf16x8*>(xb + ar);
    }
    #pragma unroll
    for (int mi = 0; mi < 4; mi++)
      #pragma unroll
      for (int n = 0; n < 4; n++)
        acc[mi][n] = __builtin_amdgcn_mfma_f32_16x16x32_bf16(a[mi], bv[n], acc[mi][n], 0, 0, 0);
  }

  // ---- epilogue: bf16 stores into row slots (+ fused BN stats for MODE 1) ----
  float pa = (MODE == 0) ? prelu_a[0] : 0.0f;
  #pragma unroll
  for (int mi = 0; mi < 4; mi++) {
    #pragma unroll
    for (int r = 0; r < 4; r++) {
      int g = wg * 64 + mi * 16 + q * 4 + r;
      float bvs = bias[g];
      size_t orow = ((size_t)(b * H_ + g)) * 32768 + jb + wj * 64 + ln;
      float s1 = 0.0f, s2 = 0.0f;
      #pragma unroll
      for (int n = 0; n < 4; n++) {
        float v = acc[mi][n][r] + bvs;
        if (MODE == 0) v = (v > 0.0f) ? v : pa * v;
        outb[orow + n * 16] = (unsigned short)f2bf(v);
        if (MODE == 1) { s1 += v; s2 = fmaf(v, v, s2); }
      }
      if (MODE == 1) {
        #pragma unroll
        for (int off = 1; off < 16; off <<= 1) {
          s1 += __shfl_xor(s1, off);
          s2 += __shfl_xor(s2, off);
        }
        if (ln == 0) {
          atomicAdd(&bs1[g], s1);
          atomicAdd(&bs2[g], s2);
        }
      }
    }
  }
  if (MODE == 1) {
    __syncthreads();
    if (tid < 128) {
      atomicAdd(&bnsum[tid], bs1[tid]);
      atomicAdd(&bnsumsq[tid], bs2[tid]);
    }
  }
}

// ---------------------------------------------------------------------------
// scan4b: chunked SSM scan, bf16 row in LDS, 4-way mode split, software-
// pipelined LDS reads (prefetch next uint4 = 8 elems before processing
// current).  1024 thr: thread = (chunk c = tid>>2, mode m = tid&3).
// Combine: in-wave shfl_up Kogge-Stone + LDS wave-aggregate fold.
// Swizzle: uint idx ^ ((chunk&7)<<2) — 16B-granular, uint4-safe.
// ---------------------------------------------------------------------------
__global__ __launch_bounds__(1024) void scan4_kernel(
    unsigned short* ub, const float* __restrict__ consts, const float* __restrict__ Dp)
{
  __shared__ __align__(16) unsigned int rowl[8192];   // 16384 bf16, swizzled
  __shared__ float agg[16][32];            // wave aggregates [wave][m*8+2k(+1)]
  int tid = threadIdx.x;
  int row = blockIdx.x;
  int h   = row & 127;
  const float* cb = consts + h * 96;
  unsigned int* grow = (unsigned int*)ub + (size_t)row * 16384;

  // ---- stage in ----
  #pragma unroll
  for (int rd = 0; rd < 2; rd++) {
    int u0   = rd * 4096 + tid * 4;
    uint4 v  = *reinterpret_cast<const uint4*>(grow + u0);
    int phys = u0 ^ (((u0 >> 5) & 7) << 2);
    *reinterpret_cast<uint4*>(&rowl[phys]) = v;
  }
  __syncthreads();

  int c     = tid >> 2;          // chunk 0..255
  int m     = tid & 3;           // mode group (modes 4m..4m+3)
  int lane  = tid & 63;
  int cl    = lane >> 2;         // chunk-local within wave, 0..15
  int wv    = tid >> 6;          // wave id 0..15
  int cbase = c * 32;
  int swz   = (c & 7) << 2;

  float wre[4], wim[4];
  #pragma unroll
  for (int k = 0; k < 4; k++) { wre[k] = cb[4*m+k]; wim[k] = cb[16+4*m+k]; }

  float sre[4] = {0.f,0.f,0.f,0.f}, sim[4] = {0.f,0.f,0.f,0.f};

  #define UPD_(uval) { \
    _Pragma("unroll") \
    for (int k = 0; k < 4; k++) { \
      float nr = fmaf(wre[k], sre[k], fmaf(-wim[k], sim[k], (uval))); \
      float ni = fmaf(wre[k], sim[k], wim[k] * sre[k]); \
      sre[k] = nr; sim[k] = ni; } }

  // ---- phase 1: local chunk states, pipelined (8 elems / iter) ----
  {
    uint4 pv = *reinterpret_cast<uint4*>(&rowl[cbase ^ swz]);
    #pragma unroll
    for (int e4 = 0; e4 < 8; e4++) {
      uint4 nxt = pv;
      if (e4 < 7) nxt = *reinterpret_cast<uint4*>(&rowl[(cbase + 4 * (e4 + 1)) ^ swz]);
      unsigned int wd[4] = {pv.x, pv.y, pv.z, pv.w};
      #pragma unroll
      for (int p = 0; p < 4; p++) {
        float u0 = __uint_as_float(wd[p] << 16);
        float u1 = __uint_as_float(wd[p] & 0xFFFF0000u);
        UPD_(u0); UPD_(u1);
      }
      pv = nxt;
    }
  }

  // ---- in-wave Kogge-Stone over 16 chunks via shfl_up; also accumulate
  //      pw = wc^cl for the phase-2 seed ----
  float mre[4], mim[4];
  #pragma unroll
  for (int k = 0; k < 4; k++) { mre[k] = cb[64+4*m+k]; mim[k] = cb[80+4*m+k]; }
  float pwr[4] = {1.f,1.f,1.f,1.f}, pwi[4] = {0.f,0.f,0.f,0.f};
  #pragma unroll
  for (int s = 0; s < 4; s++) {
    int off = 1 << s;
    bool bit = (cl >> s) & 1;
    #pragma unroll
    for (int k = 0; k < 4; k++) {          // pw *= wc^(2^s) if bit
      float tr = fmaf(pwr[k], mre[k], -(pwi[k] * mim[k]));
      float ti = fmaf(pwr[k], mim[k],  (pwi[k] * mre[k]));
      pwr[k] = bit ? tr : pwr[k];
      pwi[k] = bit ? ti : pwi[k];
    }
    bool act = (cl >= off);
    #pragma unroll
    for (int k = 0; k < 4; k++) {
      float pr = __shfl_up(sre[k], 4 * off, 64);
      float pi = __shfl_up(sim[k], 4 * off, 64);
      float nr = fmaf(mre[k], pr, fmaf(-mim[k], pi, sre[k]));
      float ni = fmaf(mre[k], pi, fmaf( mim[k], pr, sim[k]));
      sre[k] = act ? nr : sre[k];
      sim[k] = act ? ni : sim[k];
    }
    #pragma unroll
    for (int k = 0; k < 4; k++) {          // square multiplier
      float r = mre[k], i2 = mim[k];
      mre[k] = fmaf(r, r, -(i2 * i2));
      mim[k] = 2.0f * r * i2;
    }
  }
  // mre/mim now hold wc^16 (one wave span)

  // ---- publish wave aggregates, fold preceding waves ----
  if (cl == 15) {
    #pragma unroll
    for (int k = 0; k < 4; k++) {
      agg[wv][m * 8 + 2 * k]     = sre[k];
      agg[wv][m * 8 + 2 * k + 1] = sim[k];
    }
  }
  __syncthreads();
  float Cr[4] = {0.f,0.f,0.f,0.f}, Ci[4] = {0.f,0.f,0.f,0.f};
  for (int wp = 0; wp < wv; wp++) {        // wave-uniform trip count
    #pragma unroll
    for (int k = 0; k < 4; k++) {
      float ar = agg[wp][m * 8 + 2 * k];
      float ai = agg[wp][m * 8 + 2 * k + 1];
      float nr = fmaf(mre[k], Cr[k], fmaf(-mim[k], Ci[k], ar));
      float ni = fmaf(mre[k], Ci[k], fmaf( mim[k], Cr[k], ai));
      Cr[k] = nr; Ci[k] = ni;
    }
  }

  // ---- phase-2 seed: I_{c-1} = I_loc_{c-1} + wc^cl * C ----
  #pragma unroll
  for (int k = 0; k < 4; k++) {
    float er = __shfl_up(sre[k], 4, 64);
    float ei = __shfl_up(sim[k], 4, 64);
    float br = (cl == 0) ? 0.0f : er;
    float bi = (cl == 0) ? 0.0f : ei;
    sre[k] = fmaf(pwr[k], Cr[k], fmaf(-pwi[k], Ci[k], br));
    sim[k] = fmaf(pwr[k], Ci[k], fmaf( pwi[k], Cr[k], bi));
  }

  // ---- phase 2: seeded re-scan, emit y, pipelined ----
  float cre[4], cim[4];
  #pragma unroll
  for (int k = 0; k < 4; k++) { cre[k] = cb[32+4*m+k]; cim[k] = cb[48+4*m+k]; }
  float Dv = Dp[h];

  #define STEP_(uval, yout) { \
    float ya = 0.0f; \
    _Pragma("unroll") \
    for (int k = 0; k < 4; k++) { \
      float nr = fmaf(wre[k], sre[k], fmaf(-wim[k], sim[k], (uval))); \
      float ni = fmaf(wre[k], sim[k], wim[k] * sre[k]); \
      sre[k] = nr; sim[k] = ni; \
      ya = fmaf(cre[k], nr, fmaf(-cim[k], ni, ya)); } \
    yout = ya; }

  {
    uint4 pv = *reinterpret_cast<uint4*>(&rowl[cbase ^ swz]);
    #pragma unroll
    for (int e4 = 0; e4 < 8; e4++) {
      int idx = (cbase + 4 * e4) ^ swz;
      uint4 nxt = pv;
      if (e4 < 7) nxt = *reinterpret_cast<uint4*>(&rowl[(cbase + 4 * (e4 + 1)) ^ swz]);
      unsigned int wd[4] = {pv.x, pv.y, pv.z, pv.w};
      unsigned int po[4];
      #pragma unroll
      for (int p = 0; p < 4; p++) {
        float u0 = __uint_as_float(wd[p] << 16);
        float u1 = __uint_as_float(wd[p] & 0xFFFF0000u);
        float y0, y1;
        STEP_(u0, y0); STEP_(u1, y1);
        y0 += __shfl_xor(y0, 1); y0 += __shfl_xor(y0, 2);
        y1 += __shfl_xor(y1, 1); y1 += __shfl_xor(y1, 2);
        y0 = fmaf(Dv, u0, 2.0f * y0);
        y1 = fmaf(Dv, u1, 2.0f * y1);
        po[p] = cvtpk(y0, y1);
      }
      if (m == 0)
        *reinterpret_cast<uint4*>(&rowl[idx]) = make_uint4(po[0], po[1], po[2], po[3]);
      pv = nxt;
    }
  }
  #undef UPD_
  #undef STEP_
  __syncthreads();

  // ---- stage out ----
  #pragma unroll
  for (int rd = 0; rd < 2; rd++) {
    int u0   = rd * 4096 + tid * 4;
    int phys = u0 ^ (((u0 >> 5) & 7) << 2);
    uint4 v  = *reinterpret_cast<const uint4*>(&rowl[phys]);
    *reinterpret_cast<uint4*>(grow + u0) = v;
  }
}

// ---------------------------------------------------------------------------
__global__ void bnfinal_kernel(const float* __restrict__ bnsum,
                               const float* __restrict__ bnsumsq,
                               float* __restrict__ meanp, float* __restrict__ invp)
{
  int g = threadIdx.x;
  if (g < H_) {
    double cnt = (double)B_ * (double)L_;
    double mu  = (double)bnsum[g] / cnt;
    double var = (double)bnsumsq[g] / cnt - mu * mu;
    meanp[g] = (float)mu;
    invp[g]  = (float)(1.0 / sqrt(var + 1e-5));
  }
}

// ---------------------------------------------------------------------------
// final2: one block per row; z bf16 -> regs, barrier, BN+FiLM+prelu+residual,
// write f32 over the same row slot (in-place safe via the barrier).
// ---------------------------------------------------------------------------
__global__ __launch_bounds__(256) void final2_kernel(
    unsigned short* __restrict__ ub, float* __restrict__ outf,
    const float* __restrict__ x,
    const float* __restrict__ meanp, const float* __restrict__ invp,
    const float* __restrict__ gact, const float* __restrict__ bact,
    const float* __restrict__ prelu2_a, const float* __restrict__ res_w)
{
  int row = blockIdx.x, tid = threadIdx.x;
  int b = row >> 7, g = row & 127;
  const unsigned int* zr = (const unsigned int*)ub + (size_t)row * 16384;
  uint4 zq0 = *reinterpret_cast<const uint4*>(zr + 0 * 1024 + tid * 4);
  uint4 zq1 = *reinterpret_cast<const uint4*>(zr + 1 * 1024 + tid * 4);
  uint4 zq2 = *reinterpret_cast<const uint4*>(zr + 2 * 1024 + tid * 4);
  uint4 zq3 = *reinterpret_cast<const uint4*>(zr + 3 * 1024 + tid * 4);
  uint4 zq4 = *reinterpret_cast<const uint4*>(zr + 4 * 1024 + tid * 4);
  uint4 zq5 = *reinterpret_cast<const uint4*>(zr + 5 * 1024 + tid * 4);
  uint4 zq6 = *reinterpret_cast<const uint4*>(zr + 6 * 1024 + tid * 4);
  uint4 zq7 = *reinterpret_cast<const uint4*>(zr + 7 * 1024 + tid * 4);
  __syncthreads();   // all z reads complete before any f32 write to the slot

  float m  = meanp[g], iv = invp[g];
  float ga = gact[b * H_ + g], bb = bact[b * H_ + g];
  float rw = res_w[g], pa = prelu2_a[0];
  const float* xr = x + (size_t)row * L_;
  float* orow = outf + (size_t)row * L_;

  uint4 zqa[8] = {zq0, zq1, zq2, zq3, zq4, zq5, zq6, zq7};
  #pragma unroll
  for (int rd = 0; rd < 8; rd++) {
    int e0 = rd * 2048 + tid * 8;
    f32x4 x0 = *reinterpret_cast<const f32x4*>(xr + e0);
    f32x4 x1 = *reinterpret_cast<const f32x4*>(xr + e0 + 4);
    unsigned int wz[4] = {zqa[rd].x, zqa[rd].y, zqa[rd].z, zqa[rd].w};
    f32x4 o0, o1;
    #pragma unroll
    for (int k = 0; k < 4; k++) {
      float z0 = bf2f(wz[k] & 0xFFFFu), z1 = bf2f(wz[k] >> 16);
      float v0 = fmaf((z0 - m) * iv, ga, bb);
      float v1 = fmaf((z1 - m) * iv, ga, bb);
      v0 = (v0 > 0.0f) ? v0 : pa * v0;
      v1 = (v1 > 0.0f) ? v1 : pa * v1;
      float xa = (k < 2) ? x0[2 * k] : x1[2 * k - 4];
      float xbv = (k < 2) ? x0[2 * k + 1] : x1[2 * k - 3];
      float r0 = fmaf(rw, xa, v0);
      float r1 = fmaf(rw, xbv, v1);
      if (k < 2) { o0[2 * k] = r0; o0[2 * k + 1] = r1; }
      else       { o1[2 * k - 4] = r0; o1[2 * k - 3] = r1; }
    }
    *reinterpret_cast<f32x4*>(orow + e0)     = o0;
    *reinterpret_cast<f32x4*>(orow + e0 + 4) = o1;
  }
}

// ---------------------------------------------------------------------------
extern "C" void kernel_launch(void* const* d_in, const int* in_sizes, int n_in,
                              void* d_out, int out_size, void* d_ws, size_t ws_size,
                              hipStream_t stream)
{
  const float* x        = (const float*)d_in[0];
  const float* cond     = (const float*)d_in[1];
  const float* lin_w    = (const float*)d_in[2];
  const float* lin_b    = (const float*)d_in[3];
  const float* prelu1_a = (const float*)d_in[4];
  const float* log_dt   = (const float*)d_in[5];
  const float* log_A    = (const float*)d_in[6];
  const float* A_imag   = (const float*)d_in[7];
  const float* C_re     = (const float*)d_in[8];
  const float* C_im     = (const float*)d_in[9];
  const float* Dp       = (const float*)d_in[10];
  const float* out_w    = (const float*)d_in[11];
  const float* out_b    = (const float*)d_in[12];
  const float* film_w   = (const float*)d_in[13];
  const float* film_b   = (const float*)d_in[14];
  const float* prelu2_a = (const float*)d_in[15];
  const float* res_w    = (const float*)d_in[16];
  float* outf = (float*)d_out;
  unsigned short* ubuf = (unsigned short*)d_out;

  char* wsb = (char*)d_ws;               // ~125 KB total
  float* consts         = (float*)(wsb + 0);        // 12288 f32 = 48 KB
  unsigned short* wA16  = (unsigned short*)(wsb + 49152);   // 32 KB
  unsigned short* wB16  = (unsigned short*)(wsb + 81920);   // 32 KB
  float* gact           = (float*)(wsb + 114688);   // 4 KB
  float* bact           = (float*)(wsb + 118784);   // 4 KB
  float* meanp          = (float*)(wsb + 122880);   // 512 B
  float* invp           = (float*)(wsb + 123392);   // 512 B
  float* bnsum          = (float*)(wsb + 123904);   // 512 B
  float* bnsumsq        = (float*)(wsb + 124416);   // 512 B

  prep2_kernel<<<18, 256, 0, stream>>>(lin_w, out_w, log_dt, log_A, A_imag, C_re, C_im,
                                       cond, film_w, film_b, wA16, wB16, consts, gact, bact,
                                       bnsum, bnsumsq);
  // lin + prelu: x (f32) -> u (bf16 row slots in d_out)
  mgemm_kernel<0><<<1024, 256, 0, stream>>>(x, wA16, lin_b, prelu1_a, ubuf,
                                            nullptr, nullptr);
  // SSM scan: u -> y, bf16, in place per row
  scan4_kernel<<<1024, 1024, 0, stream>>>(ubuf, consts, Dp);
  // out layer + bias + fused BN stats: y (bf16) -> z (bf16), in place
  mgemm_kernel<1><<<1024, 256, 0, stream>>>(ubuf, wB16, out_b, nullptr, ubuf,
                                            bnsum, bnsumsq);
  bnfinal_kernel<<<1, 128, 0, stream>>>(bnsum, bnsumsq, meanp, invp);
  // BN + FiLM + prelu2 + residual: z (bf16) -> out (f32), in place per row
  final2_kernel<<<1024, 256, 0, stream>>>(ubuf, outf, x, meanp, invp, gact, bact,
                                          prelu2_a, res_w);
}

// Round 12
// 334.589 us; speedup vs baseline: 1.0784x; 1.0784x over previous
//
#include <hip/hip_runtime.h>
#include <math.h>

#define B_ 8
#define H_ 128
#define L_ 16384
#define N_ 16
#define CHUNK_ 64
#define NCH_ 256   // L_ / CHUNK_

typedef float f32x4 __attribute__((ext_vector_type(4)));
typedef short bf16x8 __attribute__((ext_vector_type(8)));

static __device__ __forceinline__ unsigned int f2bf(float f) {
  unsigned int u = __float_as_uint(f);
  return (u + 0x7FFFu + ((u >> 16) & 1u)) >> 16;   // RNE bf16
}
static __device__ __forceinline__ float bf2f(unsigned int us) {
  return __uint_as_float(us << 16);
}
// packed 2xbf16 from 2 f32 in one instruction
static __device__ __forceinline__ unsigned int cvtpk(float lo, float hi) {
  unsigned int r;
  asm("v_cvt_pk_bf16_f32 %0, %1, %2" : "=v"(r) : "v"(lo), "v"(hi));
  return r;
}

// ---------------------------------------------------------------------------
// prep2: parallel weight bf16 conversion + SSM constants + FiLM + BN zero
// ---------------------------------------------------------------------------
__global__ __launch_bounds__(256) void prep2_kernel(
    const float* __restrict__ lin_w, const float* __restrict__ out_w,
    const float* __restrict__ log_dt, const float* __restrict__ log_A_real,
    const float* __restrict__ A_imag, const float* __restrict__ C_re,
    const float* __restrict__ C_im, const float* __restrict__ cond,
    const float* __restrict__ film_w, const float* __restrict__ film_b,
    unsigned short* __restrict__ wA16, unsigned short* __restrict__ wB16,
    float* __restrict__ consts,
    float* __restrict__ gact, float* __restrict__ bact,
    float* __restrict__ bnsum, float* __restrict__ bnsumsq)
{
  int blk = blockIdx.x, t = threadIdx.x;
  if (blk < 16) {
    int base = blk * 1024;
    #pragma unroll
    for (int it = 0; it < 4; it++) {
      int i = base + it * 256 + t;
      wA16[i] = (unsigned short)f2bf(lin_w[i]);
      wB16[i] = (unsigned short)f2bf(out_w[i]);
    }
  } else if (blk == 16) {
    for (int i = t; i < H_ * N_; i += 256) {
      int h = i >> 4, n = i & 15;
      float dt  = expf(log_dt[h]);
      float Are = -expf(log_A_real[i]);
      float Aim = A_imag[i];
      float dre = dt * Are, dim = dt * Aim;
      float er  = expf(dre);
      float wre = er * cosf(dim);
      float wim = er * sinf(dim);
      float den = Are * Are + Aim * Aim;
      float nre = wre - 1.0f, nim = wim;
      float dBre = (nre * Are + nim * Aim) / den;
      float dBim = (nim * Are - nre * Aim) / den;
      float cr = C_re[i], ci = C_im[i];
      float cere = cr * dBre - ci * dBim;
      float ceim = cr * dBim + ci * dBre;
      float e2   = expf((float)CHUNK_ * dre);
      float wcre = e2 * cosf((float)CHUNK_ * dim);
      float wcim = e2 * sinf((float)CHUNK_ * dim);
      float* cb = consts + h * 96;
      cb[n]      = wre;  cb[16 + n] = wim;
      cb[32 + n] = cere; cb[48 + n] = ceim;
      cb[64 + n] = wcre; cb[80 + n] = wcim;
    }
    if (t < 128) bnsum[t] = 0.0f;
    else         bnsumsq[t - 128] = 0.0f;
  } else {
    for (int i = t; i < B_ * 2 * H_; i += 256) {
      int b = i >> 8, k = i & 255;
      float acc = film_b[k];
      #pragma unroll
      for (int c = 0; c < 4; c++) acc += cond[b * 4 + c] * film_w[k * 4 + c];
      if (k < H_) gact[b * H_ + k] = acc;
      else        bact[b * H_ + (k - H_)] = acc;
    }
  }
}

// ---------------------------------------------------------------------------
// MFMA GEMM, 128g x 128j tile, K=128.  OPERAND-SWAPPED: D = mfma(X, W) puts
// j in D's ROW dim (reg-quad = 4 consecutive j) -> uint2 stores (16x8B vs
// 64x2B per thread).  MODE 0: x f32 -> u bf16 (+prelu).  MODE 1: y bf16 ->
// z bf16 (+bias) + fused BN partials (LDS + 1 f32 atomic/g/block).
// In-place safe: block reads all h rows of cols [jb,jb+128) before stores.
// ---------------------------------------------------------------------------
template<int MODE>
__global__ __launch_bounds__(256) void mgemm_kernel(
    const void* inv, const unsigned short* __restrict__ w16,
    const float* __restrict__ bias, const float* __restrict__ prelu_a,
    unsigned short* __restrict__ outb,
    float* __restrict__ bnsum, float* __restrict__ bnsumsq)
{
  __shared__ __align__(16) unsigned short xT[128 * 128];  // 32KB swizzled [j][h]
  __shared__ float bs1[128], bs2[128];
  char* xb = (char*)xT;
  int tid = threadIdx.x;
  int blk = blockIdx.x;
  int b   = blk >> 7;
  int jb  = (blk & 127) << 7;

  if (MODE == 1 && tid < 128) { bs1[tid] = 0.0f; bs2[tid] = 0.0f; }

  // ---- stage x^T tile (128j x 128h) as bf16, XOR-swizzled ----
  {
    int hp = tid >> 4;        // h-group: h0 = hp*8
    int jq = tid & 15;        // j-group: j0 = jq*8
    int h0 = hp << 3;
    int j0 = jq << 3;
    if (MODE == 0) {
      const float* inb = (const float*)inv + ((size_t)b * H_) * L_ + jb;
      f32x4 r[8][2];
      #pragma unroll
      for (int rr = 0; rr < 8; rr++) {
        r[rr][0] = *reinterpret_cast<const f32x4*>(&inb[(size_t)(h0 + rr) * L_ + j0]);
        r[rr][1] = *reinterpret_cast<const f32x4*>(&inb[(size_t)(h0 + rr) * L_ + j0 + 4]);
      }
      #pragma unroll
      for (int jj = 0; jj < 8; jj++) {
        int j = j0 + jj;
        uint4 pk;
        #define GE_(rr) ((jj < 4) ? r[rr][0][jj] : r[rr][1][jj - 4])
        pk.x = cvtpk(GE_(0), GE_(1));
        pk.y = cvtpk(GE_(2), GE_(3));
        pk.z = cvtpk(GE_(4), GE_(5));
        pk.w = cvtpk(GE_(6), GE_(7));
        #undef GE_
        int addr = j * 256 + ((hp << 4) ^ ((j & 15) << 4));
        *reinterpret_cast<uint4*>(xb + addr) = pk;
      }
    } else {
      const unsigned short* ub = (const unsigned short*)inv;
      uint4 rv[8];
      #pragma unroll
      for (int rr = 0; rr < 8; rr++)
        rv[rr] = *reinterpret_cast<const uint4*>(
            ub + ((size_t)(b * H_ + h0 + rr)) * 32768 + jb + j0);
      #pragma unroll
      for (int jj = 0; jj < 8; jj++) {
        int j = j0 + jj;
        unsigned int sel = (jj & 1) ? 0x07060302u : 0x05040100u;
        uint4 pk;
        #define WD_(rr) ((jj >> 1) == 0 ? rv[rr].x : (jj >> 1) == 1 ? rv[rr].y : \
                         (jj >> 1) == 2 ? rv[rr].z : rv[rr].w)
        pk.x = __builtin_amdgcn_perm(WD_(1), WD_(0), sel);
        pk.y = __builtin_amdgcn_perm(WD_(3), WD_(2), sel);
        pk.z = __builtin_amdgcn_perm(WD_(5), WD_(4), sel);
        pk.w = __builtin_amdgcn_perm(WD_(7), WD_(6), sel);
        #undef WD_
        int addr = j * 256 + ((hp << 4) ^ ((j & 15) << 4));
        *reinterpret_cast<uint4*>(xb + addr) = pk;
      }
    }
  }
  __syncthreads();

  // ---- MFMA compute: wave tile 64j x 64g, acc[ji][gi] ----
  int lane = tid & 63;
  int w    = tid >> 6;
  int wg   = w >> 1;
  int wj   = w & 1;
  int ln   = lane & 15;
  int q    = lane >> 4;
  f32x4 acc[4][4];
  #pragma unroll
  for (int ji = 0; ji < 4; ji++)
    #pragma unroll
    for (int gi = 0; gi < 4; gi++) acc[ji][gi] = (f32x4)0.0f;

  #pragma unroll
  for (int kb = 0; kb < 4; kb++) {
    bf16x8 a[4], bv[4];
    #pragma unroll
    for (int gi = 0; gi < 4; gi++)
      a[gi] = *reinterpret_cast<const bf16x8*>(
          &w16[(size_t)(wg * 64 + gi * 16 + ln) * 128 + kb * 32 + q * 8]);
    #pragma unroll
    for (int ji = 0; ji < 4; ji++) {
      int jl = wj * 64 + ji * 16 + ln;
      int ar = jl * 256 + (((kb << 6) + (q << 4)) ^ ((jl & 15) << 4));
      bv[ji] = *reinterpret_cast<bf16x8*>(xb + ar);
    }
    // operand swap: A = x-frag (rows = j), B = w-frag (cols = g)
    #pragma unroll
    for (int ji = 0; ji < 4; ji++)
      #pragma unroll
      for (int gi = 0; gi < 4; gi++)
        acc[ji][gi] = __builtin_amdgcn_mfma_f32_16x16x32_bf16(bv[ji], a[gi], acc[ji][gi], 0, 0, 0);
  }

  // ---- epilogue: reg-quad = 4 consecutive j -> uint2 stores ----
  float pa = (MODE == 0) ? prelu_a[0] : 0.0f;
  #pragma unroll
  for (int gi = 0; gi < 4; gi++) {
    int g = wg * 64 + gi * 16 + ln;
    float bvs = bias[g];
    unsigned short* orow = outb + ((size_t)(b * H_ + g)) * 32768 + jb + wj * 64 + q * 4;
    float s1 = 0.0f, s2 = 0.0f;
    #pragma unroll
    for (int ji = 0; ji < 4; ji++) {
      float v0 = acc[ji][gi][0] + bvs;
      float v1 = acc[ji][gi][1] + bvs;
      float v2 = acc[ji][gi][2] + bvs;
      float v3 = acc[ji][gi][3] + bvs;
      if (MODE == 0) {
        v0 = (v0 > 0.0f) ? v0 : pa * v0;
        v1 = (v1 > 0.0f) ? v1 : pa * v1;
        v2 = (v2 > 0.0f) ? v2 : pa * v2;
        v3 = (v3 > 0.0f) ? v3 : pa * v3;
      }
      if (MODE == 1) {
        s1 += (v0 + v1) + (v2 + v3);
        s2 = fmaf(v0, v0, fmaf(v1, v1, fmaf(v2, v2, fmaf(v3, v3, s2))));
      }
      uint2 pk;
      pk.x = cvtpk(v0, v1);
      pk.y = cvtpk(v2, v3);
      *reinterpret_cast<uint2*>(orow + ji * 16) = pk;
    }
    if (MODE == 1) {
      s1 += __shfl_xor(s1, 16); s1 += __shfl_xor(s1, 32);
      s2 += __shfl_xor(s2, 16); s2 += __shfl_xor(s2, 32);
      if (q == 0) {
        atomicAdd(&bs1[g], s1);
        atomicAdd(&bs2[g], s2);
      }
    }
  }
  if (MODE == 1) {
    __syncthreads();
    if (tid < 128) {
      atomicAdd(&bnsum[tid], bs1[tid]);
      atomicAdd(&bnsumsq[tid], bs2[tid]);
    }
  }
}

// ---------------------------------------------------------------------------
// scan4: chunked SSM scan, bf16 row in LDS, 4-way mode split (round-8
// structure: uint2 reads, immediate conditional store — proven 121us, no
// spill; round-11's uint4 prefetch spilled ~150MB scratch).
// 1024 thr: thread = (chunk c = tid>>2, mode m = tid&3).
// Combine: in-wave shfl_up Kogge-Stone + LDS wave-aggregate fold.
// ---------------------------------------------------------------------------
__global__ __launch_bounds__(1024) void scan4_kernel(
    unsigned short* ub, const float* __restrict__ consts, const float* __restrict__ Dp)
{
  __shared__ __align__(16) unsigned int rowl[8192];   // 16384 bf16, swizzled
  __shared__ float agg[16][32];            // wave aggregates [wave][m*8+2k(+1)]
  int tid = threadIdx.x;
  int row = blockIdx.x;
  int h   = row & 127;
  const float* cb = consts + h * 96;
  unsigned int* grow = (unsigned int*)ub + (size_t)row * 16384;

  // ---- stage in ----
  #pragma unroll
  for (int rd = 0; rd < 2; rd++) {
    int u0   = rd * 4096 + tid * 4;
    uint4 v  = *reinterpret_cast<const uint4*>(grow + u0);
    int phys = u0 ^ (((u0 >> 5) & 7) << 2);
    *reinterpret_cast<uint4*>(&rowl[phys]) = v;
  }
  __syncthreads();

  int c     = tid >> 2;          // chunk 0..255
  int m     = tid & 3;           // mode group (modes 4m..4m+3)
  int lane  = tid & 63;
  int cl    = lane >> 2;         // chunk-local within wave, 0..15
  int wv    = tid >> 6;          // wave id 0..15
  int cbase = c * 32;
  int swz   = (c & 7) << 2;

  float wre[4], wim[4];
  #pragma unroll
  for (int k = 0; k < 4; k++) { wre[k] = cb[4*m+k]; wim[k] = cb[16+4*m+k]; }

  float sre[4] = {0.f,0.f,0.f,0.f}, sim[4] = {0.f,0.f,0.f,0.f};

  #define UPD_(uval) { \
    _Pragma("unroll") \
    for (int k = 0; k < 4; k++) { \
      float nr = fmaf(wre[k], sre[k], fmaf(-wim[k], sim[k], (uval))); \
      float ni = fmaf(wre[k], sim[k], wim[k] * sre[k]); \
      sre[k] = nr; sim[k] = ni; } }

  // ---- phase 1: local chunk states (4 elems / iter) ----
  for (int e2 = 0; e2 < 16; e2++) {
    int idx  = (cbase + 2 * e2) ^ swz;
    uint2 pv = *reinterpret_cast<uint2*>(&rowl[idx]);
    float u0 = __uint_as_float(pv.x << 16);
    float u1 = __uint_as_float(pv.x & 0xFFFF0000u);
    float u2 = __uint_as_float(pv.y << 16);
    float u3 = __uint_as_float(pv.y & 0xFFFF0000u);
    UPD_(u0); UPD_(u1); UPD_(u2); UPD_(u3);
  }

  // ---- in-wave Kogge-Stone over 16 chunks via shfl_up; also accumulate
  //      pw = wc^cl for the phase-2 seed ----
  float mre[4], mim[4];
  #pragma unroll
  for (int k = 0; k < 4; k++) { mre[k] = cb[64+4*m+k]; mim[k] = cb[80+4*m+k]; }
  float pwr[4] = {1.f,1.f,1.f,1.f}, pwi[4] = {0.f,0.f,0.f,0.f};
  #pragma unroll
  for (int s = 0; s < 4; s++) {
    int off = 1 << s;
    bool bit = (cl >> s) & 1;
    #pragma unroll
    for (int k = 0; k < 4; k++) {          // pw *= wc^(2^s) if bit
      float tr = fmaf(pwr[k], mre[k], -(pwi[k] * mim[k]));
      float ti = fmaf(pwr[k], mim[k],  (pwi[k] * mre[k]));
      pwr[k] = bit ? tr : pwr[k];
      pwi[k] = bit ? ti : pwi[k];
    }
    bool act = (cl >= off);
    #pragma unroll
    for (int k = 0; k < 4; k++) {
      float pr = __shfl_up(sre[k], 4 * off, 64);
      float pi = __shfl_up(sim[k], 4 * off, 64);
      float nr = fmaf(mre[k], pr, fmaf(-mim[k], pi, sre[k]));
      float ni = fmaf(mre[k], pi, fmaf( mim[k], pr, sim[k]));
      sre[k] = act ? nr : sre[k];
      sim[k] = act ? ni : sim[k];
    }
    #pragma unroll
    for (int k = 0; k < 4; k++) {          // square multiplier
      float r = mre[k], i2 = mim[k];
      mre[k] = fmaf(r, r, -(i2 * i2));
      mim[k] = 2.0f * r * i2;
    }
  }
  // mre/mim now hold wc^16 (one wave span)

  // ---- publish wave aggregates, fold preceding waves ----
  if (cl == 15) {
    #pragma unroll
    for (int k = 0; k < 4; k++) {
      agg[wv][m * 8 + 2 * k]     = sre[k];
      agg[wv][m * 8 + 2 * k + 1] = sim[k];
    }
  }
  __syncthreads();
  float Cr[4] = {0.f,0.f,0.f,0.f}, Ci[4] = {0.f,0.f,0.f,0.f};
  for (int wp = 0; wp < wv; wp++) {        // wave-uniform trip count
    #pragma unroll
    for (int k = 0; k < 4; k++) {
      float ar = agg[wp][m * 8 + 2 * k];
      float ai = agg[wp][m * 8 + 2 * k + 1];
      float nr = fmaf(mre[k], Cr[k], fmaf(-mim[k], Ci[k], ar));
      float ni = fmaf(mre[k], Ci[k], fmaf( mim[k], Cr[k], ai));
      Cr[k] = nr; Ci[k] = ni;
    }
  }

  // ---- phase-2 seed: I_{c-1} = I_loc_{c-1} + wc^cl * C ----
  #pragma unroll
  for (int k = 0; k < 4; k++) {
    float er = __shfl_up(sre[k], 4, 64);
    float ei = __shfl_up(sim[k], 4, 64);
    float br = (cl == 0) ? 0.0f : er;
    float bi = (cl == 0) ? 0.0f : ei;
    sre[k] = fmaf(pwr[k], Cr[k], fmaf(-pwi[k], Ci[k], br));
    sim[k] = fmaf(pwr[k], Ci[k], fmaf( pwi[k], Cr[k], bi));
  }

  // ---- phase 2: seeded re-scan, emit y ----
  float cre[4], cim[4];
  #pragma unroll
  for (int k = 0; k < 4; k++) { cre[k] = cb[32+4*m+k]; cim[k] = cb[48+4*m+k]; }
  float Dv = Dp[h];

  #define STEP_(uval, yout) { \
    float ya = 0.0f; \
    _Pragma("unroll") \
    for (int k = 0; k < 4; k++) { \
      float nr = fmaf(wre[k], sre[k], fmaf(-wim[k], sim[k], (uval))); \
      float ni = fmaf(wre[k], sim[k], wim[k] * sre[k]); \
      sre[k] = nr; sim[k] = ni; \
      ya = fmaf(cre[k], nr, fmaf(-cim[k], ni, ya)); } \
    yout = ya; }

  for (int e2 = 0; e2 < 16; e2++) {
    int idx  = (cbase + 2 * e2) ^ swz;
    uint2 pv = *reinterpret_cast<uint2*>(&rowl[idx]);
    float u0 = __uint_as_float(pv.x << 16);
    float u1 = __uint_as_float(pv.x & 0xFFFF0000u);
    float u2 = __uint_as_float(pv.y << 16);
    float u3 = __uint_as_float(pv.y & 0xFFFF0000u);
    float y0, y1, y2, y3;
    STEP_(u0, y0); STEP_(u1, y1); STEP_(u2, y2); STEP_(u3, y3);
    y0 += __shfl_xor(y0, 1); y0 += __shfl_xor(y0, 2);
    y1 += __shfl_xor(y1, 1); y1 += __shfl_xor(y1, 2);
    y2 += __shfl_xor(y2, 1); y2 += __shfl_xor(y2, 2);
    y3 += __shfl_xor(y3, 1); y3 += __shfl_xor(y3, 2);
    if (m == 0) {
      y0 = fmaf(Dv, u0, 2.0f * y0);
      y1 = fmaf(Dv, u1, 2.0f * y1);
      y2 = fmaf(Dv, u2, 2.0f * y2);
      y3 = fmaf(Dv, u3, 2.0f * y3);
      uint2 pk;
      pk.x = cvtpk(y0, y1);
      pk.y = cvtpk(y2, y3);
      *reinterpret_cast<uint2*>(&rowl[idx]) = pk;
    }
  }
  #undef UPD_
  #undef STEP_
  __syncthreads();

  // ---- stage out ----
  #pragma unroll
  for (int rd = 0; rd < 2; rd++) {
    int u0   = rd * 4096 + tid * 4;
    int phys = u0 ^ (((u0 >> 5) & 7) << 2);
    uint4 v  = *reinterpret_cast<const uint4*>(&rowl[phys]);
    *reinterpret_cast<uint4*>(grow + u0) = v;
  }
}

// ---------------------------------------------------------------------------
__global__ void bnfinal_kernel(const float* __restrict__ bnsum,
                               const float* __restrict__ bnsumsq,
                               float* __restrict__ meanp, float* __restrict__ invp)
{
  int g = threadIdx.x;
  if (g < H_) {
    double cnt = (double)B_ * (double)L_;
    double mu  = (double)bnsum[g] / cnt;
    double var = (double)bnsumsq[g] / cnt - mu * mu;
    meanp[g] = (float)mu;
    invp[g]  = (float)(1.0 / sqrt(var + 1e-5));
  }
}

// ---------------------------------------------------------------------------
// final2: one block per row; z bf16 -> regs, barrier, BN+FiLM+prelu+residual,
// write f32 over the same row slot (in-place safe via the barrier).
// ---------------------------------------------------------------------------
__global__ __launch_bounds__(256) void final2_kernel(
    unsigned short* __restrict__ ub, float* __restrict__ outf,
    const float* __restrict__ x,
    const float* __restrict__ meanp, const float* __restrict__ invp,
    const float* __restrict__ gact, const float* __restrict__ bact,
    const float* __restrict__ prelu2_a, const float* __restrict__ res_w)
{
  int row = blockIdx.x, tid = threadIdx.x;
  int b = row >> 7, g = row & 127;
  const unsigned int* zr = (const unsigned int*)ub + (size_t)row * 16384;
  uint4 zq0 = *reinterpret_cast<const uint4*>(zr + 0 * 1024 + tid * 4);
  uint4 zq1 = *reinterpret_cast<const uint4*>(zr + 1 * 1024 + tid * 4);
  uint4 zq2 = *reinterpret_cast<const uint4*>(zr + 2 * 1024 + tid * 4);
  uint4 zq3 = *reinterpret_cast<const uint4*>(zr + 3 * 1024 + tid * 4);
  uint4 zq4 = *reinterpret_cast<const uint4*>(zr + 4 * 1024 + tid * 4);
  uint4 zq5 = *reinterpret_cast<const uint4*>(zr + 5 * 1024 + tid * 4);
  uint4 zq6 = *reinterpret_cast<const uint4*>(zr + 6 * 1024 + tid * 4);
  uint4 zq7 = *reinterpret_cast<const uint4*>(zr + 7 * 1024 + tid * 4);
  __syncthreads();   // all z reads complete before any f32 write to the slot

  float m  = meanp[g], iv = invp[g];
  float ga = gact[b * H_ + g], bb = bact[b * H_ + g];
  float rw = res_w[g], pa = prelu2_a[0];
  const float* xr = x + (size_t)row * L_;
  float* orow = outf + (size_t)row * L_;

  uint4 zqa[8] = {zq0, zq1, zq2, zq3, zq4, zq5, zq6, zq7};
  #pragma unroll
  for (int rd = 0; rd < 8; rd++) {
    int e0 = rd * 2048 + tid * 8;
    f32x4 x0 = *reinterpret_cast<const f32x4*>(xr + e0);
    f32x4 x1 = *reinterpret_cast<const f32x4*>(xr + e0 + 4);
    unsigned int wz[4] = {zqa[rd].x, zqa[rd].y, zqa[rd].z, zqa[rd].w};
    f32x4 o0, o1;
    #pragma unroll
    for (int k = 0; k < 4; k++) {
      float z0 = bf2f(wz[k] & 0xFFFFu), z1 = bf2f(wz[k] >> 16);
      float v0 = fmaf((z0 - m) * iv, ga, bb);
      float v1 = fmaf((z1 - m) * iv, ga, bb);
      v0 = (v0 > 0.0f) ? v0 : pa * v0;
      v1 = (v1 > 0.0f) ? v1 : pa * v1;
      float xa = (k < 2) ? x0[2 * k] : x1[2 * k - 4];
      float xbv = (k < 2) ? x0[2 * k + 1] : x1[2 * k - 3];
      float r0 = fmaf(rw, xa, v0);
      float r1 = fmaf(rw, xbv, v1);
      if (k < 2) { o0[2 * k] = r0; o0[2 * k + 1] = r1; }
      else       { o1[2 * k - 4] = r0; o1[2 * k - 3] = r1; }
    }
    *reinterpret_cast<f32x4*>(orow + e0)     = o0;
    *reinterpret_cast<f32x4*>(orow + e0 + 4) = o1;
  }
}

// ---------------------------------------------------------------------------
extern "C" void kernel_launch(void* const* d_in, const int* in_sizes, int n_in,
                              void* d_out, int out_size, void* d_ws, size_t ws_size,
                              hipStream_t stream)
{
  const float* x        = (const float*)d_in[0];
  const float* cond     = (const float*)d_in[1];
  const float* lin_w    = (const float*)d_in[2];
  const float* lin_b    = (const float*)d_in[3];
  const float* prelu1_a = (const float*)d_in[4];
  const float* log_dt   = (const float*)d_in[5];
  const float* log_A    = (const float*)d_in[6];
  const float* A_imag   = (const float*)d_in[7];
  const float* C_re     = (const float*)d_in[8];
  const float* C_im     = (const float*)d_in[9];
  const float* Dp       = (const float*)d_in[10];
  const float* out_w    = (const float*)d_in[11];
  const float* out_b    = (const float*)d_in[12];
  const float* film_w   = (const float*)d_in[13];
  const float* film_b   = (const float*)d_in[14];
  const float* prelu2_a = (const float*)d_in[15];
  const float* res_w    = (const float*)d_in[16];
  float* outf = (float*)d_out;
  unsigned short* ubuf = (unsigned short*)d_out;

  char* wsb = (char*)d_ws;               // ~125 KB total
  float* consts         = (float*)(wsb + 0);        // 12288 f32 = 48 KB
  unsigned short* wA16  = (unsigned short*)(wsb + 49152);   // 32 KB
  unsigned short* wB16  = (unsigned short*)(wsb + 81920);   // 32 KB
  float* gact           = (float*)(wsb + 114688);   // 4 KB
  float* bact           = (float*)(wsb + 118784);   // 4 KB
  float* meanp          = (float*)(wsb + 122880);   // 512 B
  float* invp           = (float*)(wsb + 123392);   // 512 B
  float* bnsum          = (float*)(wsb + 123904);   // 512 B
  float* bnsumsq        = (float*)(wsb + 124416);   // 512 B

  prep2_kernel<<<18, 256, 0, stream>>>(lin_w, out_w, log_dt, log_A, A_imag, C_re, C_im,
                                       cond, film_w, film_b, wA16, wB16, consts, gact, bact,
                                       bnsum, bnsumsq);
  // lin + prelu: x (f32) -> u (bf16 row slots in d_out)
  mgemm_kernel<0><<<1024, 256, 0, stream>>>(x, wA16, lin_b, prelu1_a, ubuf,
                                            nullptr, nullptr);
  // SSM scan: u -> y, bf16, in place per row
  scan4_kernel<<<1024, 1024, 0, stream>>>(ubuf, consts, Dp);
  // out layer + bias + fused BN stats: y (bf16) -> z (bf16), in place
  mgemm_kernel<1><<<1024, 256, 0, stream>>>(ubuf, wB16, out_b, nullptr, ubuf,
                                            bnsum, bnsumsq);
  bnfinal_kernel<<<1, 128, 0, stream>>>(bnsum, bnsumsq, meanp, invp);
  // BN + FiLM + prelu2 + residual: z (bf16) -> out (f32), in place per row
  final2_kernel<<<1024, 256, 0, stream>>>(ubuf, outf, x, meanp, invp, gact, bact,
                                          prelu2_a, res_w);
}